// Round 5
// baseline (642.947 us; speedup 1.0000x reference)
//
#include <hip/hip_runtime.h>
#include <hip/hip_bf16.h>

// Problem constants
#define OUT_F 11008   // N
#define IN_F  4096    // K
#define M_DIM 4096    // 4 * 1024

typedef __attribute__((ext_vector_type(8))) short bf16x8;          // MFMA A/B frag
typedef __attribute__((ext_vector_type(4))) float f32x4;           // MFMA C/D frag
typedef __attribute__((ext_vector_type(8))) unsigned short us8;    // 16B of bf16 bits

// ---------------------------------------------------------------------------
// Kernel 1 (fused prep): blocks [0,8192) convert x fp32->bf16 (8 elems/thr);
// blocks [8192, 8192+11008) unpack 2-bit weights -> bf16 [OUT_F][IN_F].
// ---------------------------------------------------------------------------
__device__ __forceinline__ unsigned short f2bf_rne(float f) {
    unsigned u = __builtin_bit_cast(unsigned, f);
    u += 0x7fffu + ((u >> 16) & 1u);
    return (unsigned short)(u >> 16);
}

__global__ void prep_kernel(const float* __restrict__ x,
                            unsigned short* __restrict__ xb,
                            const int* __restrict__ pw,
                            unsigned short* __restrict__ wb) {
    if (blockIdx.x < 8192) {
        size_t i = ((size_t)blockIdx.x * blockDim.x + threadIdx.x) * 8;
        float4 a = *(const float4*)(x + i);
        float4 b = *(const float4*)(x + i + 4);
        us8 o;
        o[0] = f2bf_rne(a.x); o[1] = f2bf_rne(a.y);
        o[2] = f2bf_rne(a.z); o[3] = f2bf_rne(a.w);
        o[4] = f2bf_rne(b.x); o[5] = f2bf_rne(b.y);
        o[6] = f2bf_rne(b.z); o[7] = f2bf_rne(b.w);
        *(us8*)(xb + i) = o;
    } else {
        size_t i = ((size_t)(blockIdx.x - 8192)) * blockDim.x + threadIdx.x;
        int4 v = ((const int4*)pw)[i];
        const unsigned long long LUT = 0x40003F800000BF80ull;
        us8 o0, o1;
#pragma unroll
        for (int j = 0; j < 4; j++) {
            o0[j]     = (unsigned short)(LUT >> (((v.x >> (2 * j)) & 3) * 16));
            o0[4 + j] = (unsigned short)(LUT >> (((v.y >> (2 * j)) & 3) * 16));
            o1[j]     = (unsigned short)(LUT >> (((v.z >> (2 * j)) & 3) * 16));
            o1[4 + j] = (unsigned short)(LUT >> (((v.w >> (2 * j)) & 3) * 16));
        }
        ((us8*)wb)[i * 2]     = o0;
        ((us8*)wb)[i * 2 + 1] = o1;
    }
}

// ---------------------------------------------------------------------------
// Kernel 2: bf16 GEMM, 256x256 tile, BK=64, 8 waves (2x4 of 128x64), with
// REGISTER-LEVEL FRAGMENT PIPELINING (round-5 theory).
//
// R1/R2/R4 all hit 42% MfmaUtil with wildly different barrier/vmcnt
// structures: the invariant was "ds_read frags, then immediately MFMA them"
// -> lockstep CU-wide alternation of LDS-burst and MFMA-burst, fully
// serialized (measured 5400 cyc/K-tile = 1152+1242 per half, summed).
// Fix: quarter-tile (16-MFMA) software pipeline: while quarter Qi's MFMAs
// run on registers, the ds_reads for Q(i+1) are in flight (no consumer for
// a full MFMA burst -> compiler emits counted lgkm waits, reads hide).
//
// Frag registers (fits 2 waves/SIMD = 256 VGPR budget incl. 128 acc):
//   aC[4], aN[4]  -- A-frag ping-pong (m-half x k-half quarters)
//   bA[4] (k-half0 B), bB[4] (k-half1 B)
//
// Per K-tile kt (buf=kt&1): Quarters Q0=(h0,m0) Q1=(h0,m1) Q2=(h1,m0)
// Q3=(h1,m1).  acc rows: m0 -> acc[0..3], m1 -> acc[4..7].
//   entering: aC = Q0 frags, bA = h0 B frags (read during kt-1 from nbuf)
//   1. aN <- Q1 frags (buf);  bB <- h1 B frags (buf)
//   2. if pf: STAGE kt+1 (4 slots) -> nbuf          [8 vm loads/wave]
//   3. MFMA Q0 (aC,bA)                              [covers 1,2 issue]
//   4. aC <- Q2 frags (buf)
//   5. MFMA Q1 (aN,bA)                              [covers 4]
//   6. VMCNT(0)   own stage loads landed; cover = Q0+Q1 ~ 1240 cyc > 900
//   7. BARRIER    publishes kt+1 staged data (all waves drained)
//   8. aN <- Q3 frags (buf)
//   9. MFMA Q2 (aC,bB)                              [covers 8]
//  10. if pf: aC <- Q0(kt+1) (nbuf); bA <- h0(kt+1) B (nbuf)
//  11. MFMA Q3 (aN,bB)                              [covers 10]
//  12. BARRIER   all reads of buf lgkm-consumed (by 9/11) -> kt+1 may
//                stage into buf; step-10 reads target nbuf (kt+1's read
//                source), untouched by kt+1's stages.
// RAW(nbuf): stages issued step 2, drained step 6, published step 7,
//   read step 10.  WAR(buf): last buf reads consumed before step 12.
//
// LDS: lds[buf 2][mat A/B][khalf 2][row 256][4 slots x 8 bf16] = 128 KiB.
//  - slot for (row, seg) = seg ^ ((row>>1)&3); frag reads 2-way = free.
//  - Staging (global_load_lds, linear dest = base + lane*16): lane l covers
//    row chunk*16 + l/4, slot l&3 => fetch global seg (l&3)^((l>>3)&3).
// ---------------------------------------------------------------------------
#define VMCNT(n) do { asm volatile("s_waitcnt vmcnt(" #n ")" ::: "memory"); \
                      __builtin_amdgcn_sched_barrier(0); } while (0)

__global__ __launch_bounds__(512, 2) void gemm_kernel(
    const unsigned short* __restrict__ A,   // [M_DIM][IN_F] bf16 bits
    const unsigned short* __restrict__ B,   // [OUT_F][IN_F] bf16 bits
    float* __restrict__ C,                  // [M_DIM][OUT_F]
    const float* __restrict__ scale_ptr) {
    constexpr int K  = IN_F;
    constexpr int N  = OUT_F;
    constexpr int NT = K / 64;              // 64 K-tiles

    __shared__ unsigned short lds[2][2][2][256][32];   // 128 KiB

    const int tid  = threadIdx.x;
    const int wave = tid >> 6;
    const int lane = tid & 63;
    const int quad = lane >> 4;
    const int mrow = lane & 15;
    const int sw   = quad ^ ((mrow >> 1) & 3);          // frag-read slot

    // staging lane decomposition
    const int srow = lane >> 2;                         // 0..15 (row in chunk)
    const int sseg = (lane & 3) ^ ((lane >> 3) & 3);    // source k-seg

    // Block swizzle: XCD x owns 86 consecutive tiles = 2 bm-rows x 43 bn.
    const int lin = blockIdx.x;             // 0..687
    const int xcd = lin & 7;
    const int q   = lin >> 3;               // 0..85
    const int bm  = xcd * 2 + q / 43;       // 0..15
    const int bn  = q % 43;                 // 0..42

    const int wm = (wave >> 2) * 128;       // wave M offset in tile
    const int wn = (wave & 3) * 64;         // wave N offset in tile

    const unsigned short* Ag = A + (size_t)bm * 256 * K;
    const unsigned short* Bg = B + (size_t)bn * 256 * K;

    f32x4 acc[8][4];
#pragma unroll
    for (int i = 0; i < 8; i++)
#pragma unroll
        for (int j = 0; j < 4; j++) acc[i][j] = (f32x4){0.f, 0.f, 0.f, 0.f};

    // Stage one half-tile slot (mat, khalf) at k-elem kbase into buffer nb.
    auto STAGE = [&](int mat, int nb, int h, int kbase) {
#pragma unroll
        for (int c = 0; c < 2; ++c) {
            const int chunk = wave * 2 + c;
            const int grow  = chunk * 16 + srow;
            const unsigned short* src =
                (mat ? Bg : Ag) + (size_t)grow * K + kbase + sseg * 8;
            __builtin_amdgcn_global_load_lds(
                (const __attribute__((address_space(1))) void*)src,
                (__attribute__((address_space(3))) void*)
                    (&lds[nb][mat][h][0][0] + chunk * 512),
                16, 0, 0);
        }
    };

    // Prologue: stage K-tile 0 -> buf0; publish; preload Q0 frags + bA.
    STAGE(0, 0, 0, 0);
    STAGE(1, 0, 0, 0);
    STAGE(0, 0, 1, 32);
    STAGE(1, 0, 1, 32);
    VMCNT(0);
    __builtin_amdgcn_s_barrier();

    bf16x8 aC[4], aN[4], bA[4], bB[4];
#pragma unroll
    for (int t = 0; t < 4; ++t)
        aC[t] = *(const bf16x8*)&lds[0][0][0][wm + t * 16 + mrow][sw * 8];
#pragma unroll
    for (int j = 0; j < 4; ++j)
        bA[j] = *(const bf16x8*)&lds[0][1][0][wn + j * 16 + mrow][sw * 8];

    for (int kt = 0; kt < NT; ++kt) {
        const int  buf  = kt & 1;
        const int  nbuf = buf ^ 1;
        const bool pf   = (kt + 1 < NT);
        const int  kn   = (kt + 1) * 64;

        // 1: Q1 A-frags (h0, m-half1) + h1 B-frags
#pragma unroll
        for (int t = 0; t < 4; ++t)
            aN[t] = *(const bf16x8*)&lds[buf][0][0][wm + 64 + t * 16 + mrow][sw * 8];
#pragma unroll
        for (int j = 0; j < 4; ++j)
            bB[j] = *(const bf16x8*)&lds[buf][1][1][wn + j * 16 + mrow][sw * 8];

        // 2: stage next K-tile
        if (pf) {
            STAGE(0, nbuf, 0, kn);
            STAGE(1, nbuf, 0, kn);
            STAGE(0, nbuf, 1, kn + 32);
            STAGE(1, nbuf, 1, kn + 32);
        }

        // 3: MFMA Q0 (h0, m-half0)
#pragma unroll
        for (int t = 0; t < 4; ++t)
#pragma unroll
            for (int j = 0; j < 4; ++j)
                acc[t][j] = __builtin_amdgcn_mfma_f32_16x16x32_bf16(
                    aC[t], bA[j], acc[t][j], 0, 0, 0);

        // 4: Q2 A-frags (h1, m-half0)
#pragma unroll
        for (int t = 0; t < 4; ++t)
            aC[t] = *(const bf16x8*)&lds[buf][0][1][wm + t * 16 + mrow][sw * 8];

        // 5: MFMA Q1 (h0, m-half1)
#pragma unroll
        for (int t = 0; t < 4; ++t)
#pragma unroll
            for (int j = 0; j < 4; ++j)
                acc[4 + t][j] = __builtin_amdgcn_mfma_f32_16x16x32_bf16(
                    aN[t], bA[j], acc[4 + t][j], 0, 0, 0);

        // 6,7: publish next tile's staged data
        VMCNT(0);
        __builtin_amdgcn_s_barrier();

        // 8: Q3 A-frags (h1, m-half1)
#pragma unroll
        for (int t = 0; t < 4; ++t)
            aN[t] = *(const bf16x8*)&lds[buf][0][1][wm + 64 + t * 16 + mrow][sw * 8];

        // 9: MFMA Q2 (h1, m-half0)
#pragma unroll
        for (int t = 0; t < 4; ++t)
#pragma unroll
            for (int j = 0; j < 4; ++j)
                acc[t][j] = __builtin_amdgcn_mfma_f32_16x16x32_bf16(
                    aC[t], bB[j], acc[t][j], 0, 0, 0);

        // 10: next tile's Q0 frags + h0 B-frags (from nbuf)
        if (pf) {
#pragma unroll
            for (int t = 0; t < 4; ++t)
                aC[t] = *(const bf16x8*)&lds[nbuf][0][0][wm + t * 16 + mrow][sw * 8];
#pragma unroll
            for (int j = 0; j < 4; ++j)
                bA[j] = *(const bf16x8*)&lds[nbuf][1][0][wn + j * 16 + mrow][sw * 8];
        }

        // 11: MFMA Q3 (h1, m-half1)
#pragma unroll
        for (int t = 0; t < 4; ++t)
#pragma unroll
            for (int j = 0; j < 4; ++j)
                acc[4 + t][j] = __builtin_amdgcn_mfma_f32_16x16x32_bf16(
                    aN[t], bB[j], acc[4 + t][j], 0, 0, 0);

        // 12: tile-end barrier (frees buf for kt+1's staging)
        __builtin_amdgcn_s_barrier();
    }

    // Epilogue: C/D layout col=lane&15, row=quad*4+reg
    const float scale = *scale_ptr;
    float* Cg = C + (size_t)(bm * 256 + wm) * N + bn * 256 + wn;
#pragma unroll
    for (int i = 0; i < 8; ++i) {
#pragma unroll
        for (int j = 0; j < 4; ++j) {
#pragma unroll
            for (int r = 0; r < 4; ++r) {
                const int row = i * 16 + quad * 4 + r;
                const int col = j * 16 + mrow;
                Cg[(size_t)row * N + col] = acc[i][j][r] * scale;
            }
        }
    }
}

// ---------------------------------------------------------------------------
// Launch
// ---------------------------------------------------------------------------
extern "C" void kernel_launch(void* const* d_in, const int* in_sizes, int n_in,
                              void* d_out, int out_size, void* d_ws, size_t ws_size,
                              hipStream_t stream) {
    const float* x   = (const float*)d_in[0];     // [4,1024,4096] fp32
    const int* pw    = (const int*)d_in[1];       // [11008*4096/4] int32
    const float* wsc = (const float*)d_in[2];     // [1] fp32

    float* out = (float*)d_out;                   // [4,1024,11008] fp32

    unsigned short* xb = (unsigned short*)d_ws;
    unsigned short* wb = (unsigned short*)((char*)d_ws + (size_t)M_DIM * IN_F * 2);

    // fused prep: 8192 cvt blocks + 11008 unpack blocks
    prep_kernel<<<8192 + 11008, 256, 0, stream>>>(x, xb, pw, wb);

    // GEMM: 688 tiles = 16 (M/256) x 43 (N/256), 512 threads (8 waves)
    gemm_kernel<<<688, 512, 0, stream>>>(xb, wb, out, wsc);
}

// Round 7
// 620.149 us; speedup vs baseline: 1.0368x; 1.0368x over previous
//
#include <hip/hip_runtime.h>
#include <hip/hip_bf16.h>

// Problem constants
#define OUT_F 11008   // N
#define IN_F  4096    // K
#define M_DIM 4096    // 4 * 1024

typedef __attribute__((ext_vector_type(8))) short bf16x8;          // MFMA A/B frag
typedef __attribute__((ext_vector_type(4))) float f32x4;           // MFMA C/D frag
typedef __attribute__((ext_vector_type(8))) unsigned short us8;    // 16B of bf16 bits

// ---------------------------------------------------------------------------
// Kernel 1 (fused prep):
//  blocks [0,8192): x fp32 -> bf16 (8 elems/thread).
//  blocks [8192, 8192+2752): repack 2-bit weights tile-major.
//    Reference packing: each int32 holds FOUR 2-bit fields in its LOW byte
//    (shifts 0,2,4,6).  Repack extracts the low byte of each int32 and lays
//    bytes out as pw2[kt][row][16B], kt = K-tile of 64 k (16 bytes packed),
//    so the GEMM's packed-B staging is a contiguous 1 KB per wave.
// ---------------------------------------------------------------------------
__device__ __forceinline__ unsigned short f2bf_rne(float f) {
    unsigned u = __builtin_bit_cast(unsigned, f);
    u += 0x7fffu + ((u >> 16) & 1u);
    return (unsigned short)(u >> 16);
}

__global__ void prep_kernel(const float* __restrict__ x,
                            unsigned short* __restrict__ xb,
                            const int* __restrict__ pw,
                            unsigned char* __restrict__ pw2) {
    if (blockIdx.x < 8192) {
        size_t i = ((size_t)blockIdx.x * blockDim.x + threadIdx.x) * 8;
        float4 a = *(const float4*)(x + i);
        float4 b = *(const float4*)(x + i + 4);
        us8 o;
        o[0] = f2bf_rne(a.x); o[1] = f2bf_rne(a.y);
        o[2] = f2bf_rne(a.z); o[3] = f2bf_rne(a.w);
        o[4] = f2bf_rne(b.x); o[5] = f2bf_rne(b.y);
        o[6] = f2bf_rne(b.z); o[7] = f2bf_rne(b.w);
        *(us8*)(xb + i) = o;
    } else {
        const int kb   = blockIdx.x - 8192;      // 0..2751 = 64 kt x 43 rgrp
        const int kt   = kb & 63;
        const int rgrp = kb >> 6;
        const int row  = rgrp * 256 + threadIdx.x;
        // 16 int32 = 64 B read (contiguous per thread), 16 B packed out.
        const int4* src = (const int4*)(pw + (size_t)row * 1024 + kt * 16);
        unsigned out[4];
#pragma unroll
        for (int i = 0; i < 4; ++i) {
            int4 v = src[i];
            out[i] = (v.x & 0xFF) | ((v.y & 0xFF) << 8) |
                     ((v.z & 0xFF) << 16) | ((unsigned)v.w << 24);
        }
        *(uint4*)(pw2 + ((size_t)kt * OUT_F + row) * 16) =
            *(const uint4*)out;
    }
}

// ---------------------------------------------------------------------------
// Kernel 2: bf16 GEMM, 256x256 tile, BK=64, 8 waves, single-phase K-loop,
// with FUSED 2-bit B: stage packed B (4 KB/K-tile) + unpack in-LDS.
//
// Round-6/7 theory: rounds 0-5 (35-43% util across 5 schedule structures)
// were limited by the staged-vmem path: 2.82 GB of bf16 B+A staged per GEMM
// (7.5 TB/s sustained through L2/L3/HBM) + B (90 MB) thrashing L3 against
// C-writes (FETCH showed ~700 MB B re-fetch).  Staging B packed cuts staged
// bytes 64->36 KB/K-tile and makes B's footprint 11 MB (L3-resident).
// Unpack cost ~320 VALU-cyc/SIMD/K-tile hides under 2483 cyc of MFMA.
//
// LDS: sA[2][2][256][32] 64 KB (unchanged layout), sB same 64 KB,
//      pb[2][4096] 8 KB packed staging. Total 136 KB.
//  - slot for (row, seg) = seg ^ ((row>>1)&3); frag reads 2-way = free.
//  - A staging unchanged (global_load_lds, lane l: row chunk*16+l/4,
//    slot l&3, fetches global seg (l&3)^((l>>3)&3)).
//  - pb staging: waves 0-3, 1 instr each: lane l -> row w*64+l, 16 B
//    contiguous from tile-major pw2 (fully coalesced 1 KB).
//
// Pipeline invariant entering tile kt (c=kt&1, n=c^1):
//   sA[c]=A(kt), sB[c]=W(kt) bf16, pb[c]=packed(kt+1)   [all published]
// Body: a) stage A(kt+1)->sA[n], packed(kt+2)->pb[n]
//       b) unpack pb[c] -> sB[n]  (= W(kt+1))
//       c) compute on sA[c], sB[c]
//       d) __syncthreads (vmcnt0+lgkm0 drain, publishes sA[n],sB[n],pb[n])
// WAR/RAW: all cross-buffer, separated by the single barrier per tile;
// asymmetric per-wave load counts are safe (syncthreads drains per-wave).
//
// Unpack (512 thr): thread t -> row=t>>1, khalf h=t&1; ds_read_b64 of 8 B
// packed; per seg s (8 fields = 16 bits): 2-bit fields -> bf16 via
// mul-spread + v_perm byte-LUT (4 VALU per 2 bf16); ds_write_b128 at
// slot = s ^ ((row>>1)&3)  ==  frag-reader's expectation (seg read back
// at slot sw = quad^((mrow>>1)&3) yields global seg 'quad').
// Bank check: per iter, 16 lanes hit all 8 16-B granule positions (2 lanes
// each) -> 2-way = free (m136).
// ---------------------------------------------------------------------------
__device__ __forceinline__ void unpack_byte(unsigned b, unsigned& d_lo,
                                            unsigned& d_hi) {
    // b = 4 x 2-bit fields t0..t3 -> d_lo = bf16(t0-1),bf16(t1-1) packed,
    // d_hi = bf16(t2-1),bf16(t3-1).
    // bf16 LUT for t in {0,1,2,3} -> {-1,0,1,2}: 0xBF80,0x0000,0x3F80,0x4000
    // perm pool: sel 0-3 -> PB bytes (hi-byte LUT {BF,00,3F,40}),
    //            sel 4-7 -> PA bytes (lo-byte LUT {80,00,80,00}).
    const unsigned PA = 0x00800080u;   // lo-byte LUT (t=0..3)
    const unsigned PB = 0x403F00BFu;   // hi-byte LUT (t=0..3)  [R6 bugfix]
    unsigned m0 = (b & 0xFu) * 0x00404101u;          // bytes [t0,t0,t1,t1]
    unsigned s0 = (m0 & 0x03030303u) | 0x00040004u;  // [t0|4, t0, t1|4, t1]
    d_lo = __builtin_amdgcn_perm(PA, PB, s0);
    unsigned m1 = (b >> 4) * 0x00404101u;            // bytes [t2,t2,t3,t3]
    unsigned s1 = (m1 & 0x03030303u) | 0x00040004u;
    d_hi = __builtin_amdgcn_perm(PA, PB, s1);
}

__global__ __launch_bounds__(512, 2) void gemm_kernel(
    const unsigned short* __restrict__ A,   // [M_DIM][IN_F] bf16 bits
    const unsigned char* __restrict__ P,    // packed W, tile-major [64][OUT_F][16]
    float* __restrict__ C,                  // [M_DIM][OUT_F]
    const float* __restrict__ scale_ptr) {
    constexpr int K  = IN_F;
    constexpr int N  = OUT_F;
    constexpr int NT = K / 64;              // 64 K-tiles

    __shared__ unsigned short sA[2][2][256][32];   // 64 KB
    __shared__ unsigned short sB[2][2][256][32];   // 64 KB
    __shared__ unsigned char  pb[2][4096];         // 8 KB packed B

    const int tid  = threadIdx.x;
    const int wave = tid >> 6;
    const int lane = tid & 63;
    const int quad = lane >> 4;
    const int mrow = lane & 15;
    const int sw   = quad ^ ((mrow >> 1) & 3);          // frag-read slot

    // A-staging lane decomposition
    const int srow = lane >> 2;                         // 0..15
    const int sseg = (lane & 3) ^ ((lane >> 3) & 3);    // source k-seg

    // Block swizzle: XCD x owns 86 consecutive tiles = 2 bm-rows x 43 bn.
    const int lin = blockIdx.x;             // 0..687
    const int xcd = lin & 7;
    const int q   = lin >> 3;               // 0..85
    const int bm  = xcd * 2 + q / 43;       // 0..15
    const int bn  = q % 43;                 // 0..42

    const int wm = (wave >> 2) * 128;       // wave M offset in tile
    const int wn = (wave & 3) * 64;         // wave N offset in tile

    const unsigned short* Ag = A + (size_t)bm * 256 * K;

    f32x4 acc[8][4];
#pragma unroll
    for (int i = 0; i < 8; i++)
#pragma unroll
        for (int j = 0; j < 4; j++) acc[i][j] = (f32x4){0.f, 0.f, 0.f, 0.f};

    // Stage A K-tile (both k-halves, 4 instr/wave) into sA[nb].
    auto STAGE_A = [&](int nb, int kbase) {
#pragma unroll
        for (int h = 0; h < 2; ++h) {
#pragma unroll
            for (int c = 0; c < 2; ++c) {
                const int chunk = wave * 2 + c;
                const int grow  = chunk * 16 + srow;
                const unsigned short* src =
                    Ag + (size_t)grow * K + kbase + h * 32 + sseg * 8;
                __builtin_amdgcn_global_load_lds(
                    (const __attribute__((address_space(1))) void*)src,
                    (__attribute__((address_space(3))) void*)
                        (&sA[nb][h][0][0] + chunk * 512),
                    16, 0, 0);
            }
        }
    };
    // Stage packed B K-tile (4 KB): waves 0-3, 1 instr each, coalesced.
    auto STAGE_P = [&](int nb, int kt) {
        if (wave < 4) {
            const unsigned char* src =
                P + ((size_t)kt * N + bn * 256 + wave * 64 + lane) * 16;
            __builtin_amdgcn_global_load_lds(
                (const __attribute__((address_space(1))) void*)src,
                (__attribute__((address_space(3))) void*)(&pb[nb][wave * 1024]),
                16, 0, 0);
        }
    };
    // Unpack pb[src] (= W(ktile)) -> sB[dst] bf16, slot-swizzled.
    auto UNPACK = [&](int srcb, int dstb) {
        const int row = tid >> 1;
        const int h   = tid & 1;
        unsigned long long pk =
            *(const unsigned long long*)&pb[srcb][tid * 8];
        const int rsw = (row >> 1) & 3;
#pragma unroll
        for (int s = 0; s < 4; ++s) {
            unsigned p16 = (unsigned)(pk >> (16 * s)) & 0xFFFFu;
            unsigned d0, d1, d2, d3;
            unpack_byte(p16 & 0xFFu, d0, d1);
            unpack_byte(p16 >> 8, d2, d3);
            const int slot = s ^ rsw;
            *(uint4*)&sB[dstb][h][row][slot * 8] = (uint4){d0, d1, d2, d3};
        }
    };

    // Prologue: establish invariant for kt=0:
    //   sA[0]=A(0), sB[0]=W(0), pb[0]=packed(1)
    STAGE_A(0, 0);
    STAGE_P(1, 0);          // packed(0) -> pb[1] (scratch slot)
    __syncthreads();
    UNPACK(1, 0);           // W(0) -> sB[0]
    STAGE_P(0, 1);          // packed(1) -> pb[0]
    __syncthreads();

    for (int kt = 0; kt < NT; ++kt) {
        const int  buf  = kt & 1;
        const int  nbuf = buf ^ 1;
        const bool pf1  = (kt + 1 < NT);
        const bool pf2  = (kt + 2 < NT);

        // a) stage next A and next-next packed B
        if (pf1) STAGE_A(nbuf, (kt + 1) * 64);
        if (pf2) STAGE_P(nbuf, kt + 2);

        // b) unpack W(kt+1) from pb[buf] into sB[nbuf]
        if (pf1) UNPACK(buf, nbuf);

        // c) compute on sA[buf], sB[buf] (compiler interleaves ds/MFMA/VALU)
#pragma unroll
        for (int h = 0; h < 2; ++h) {
            bf16x8 a[8], b[4];
#pragma unroll
            for (int t = 0; t < 8; ++t)
                a[t] = *(const bf16x8*)&sA[buf][h][wm + t * 16 + mrow][sw * 8];
#pragma unroll
            for (int j = 0; j < 4; ++j)
                b[j] = *(const bf16x8*)&sB[buf][h][wn + j * 16 + mrow][sw * 8];
#pragma unroll
            for (int t = 0; t < 8; ++t)
#pragma unroll
                for (int j = 0; j < 4; ++j)
                    acc[t][j] = __builtin_amdgcn_mfma_f32_16x16x32_bf16(
                        a[t], b[j], acc[t][j], 0, 0, 0);
        }

        // d) one barrier per K-tile (vmcnt+lgkm drain implied)
        __syncthreads();
    }

    // Epilogue: C/D layout col=lane&15, row=quad*4+reg
    const float scale = *scale_ptr;
    float* Cg = C + (size_t)(bm * 256 + wm) * N + bn * 256 + wn;
#pragma unroll
    for (int i = 0; i < 8; ++i) {
#pragma unroll
        for (int j = 0; j < 4; ++j) {
#pragma unroll
            for (int r = 0; r < 4; ++r) {
                const int row = i * 16 + quad * 4 + r;
                const int col = j * 16 + mrow;
                Cg[(size_t)row * N + col] = acc[i][j][r] * scale;
            }
        }
    }
}

// ---------------------------------------------------------------------------
// Launch
// ---------------------------------------------------------------------------
extern "C" void kernel_launch(void* const* d_in, const int* in_sizes, int n_in,
                              void* d_out, int out_size, void* d_ws, size_t ws_size,
                              hipStream_t stream) {
    const float* x   = (const float*)d_in[0];     // [4,1024,4096] fp32
    const int* pw    = (const int*)d_in[1];       // [11008*4096/4] int32
    const float* wsc = (const float*)d_in[2];     // [1] fp32

    float* out = (float*)d_out;                   // [4,1024,11008] fp32

    unsigned short* xb  = (unsigned short*)d_ws;                       // 32 MB
    unsigned char*  pw2 = (unsigned char*)((char*)d_ws
                          + (size_t)M_DIM * IN_F * 2);                 // 11 MB

    // fused prep: 8192 cvt blocks + 2752 repack blocks
    prep_kernel<<<8192 + 2752, 256, 0, stream>>>(x, xb, pw, pw2);

    // GEMM: 688 tiles = 16 (M/256) x 43 (N/256), 512 threads (8 waves)
    gemm_kernel<<<688, 512, 0, stream>>>(xb, pw2, out, wsc);
}

// Round 8
// 558.191 us; speedup vs baseline: 1.1518x; 1.1110x over previous
//
#include <hip/hip_runtime.h>
#include <hip/hip_bf16.h>

// Problem constants
#define OUT_F 11008   // N
#define IN_F  4096    // K
#define M_DIM 4096    // 4 * 1024

typedef __attribute__((ext_vector_type(8))) short bf16x8;          // MFMA A/B frag
typedef __attribute__((ext_vector_type(4))) float f32x4;           // MFMA C/D frag
typedef __attribute__((ext_vector_type(8))) unsigned short us8;    // 16B of bf16 bits

// ---------------------------------------------------------------------------
// Kernel 1 (fused prep):
//  blocks [0,8192): x fp32 -> bf16 (8 elems/thread).
//  blocks [8192, 8192+688): repack 2-bit weights fragment-major:
//    pw2 (as ushort): [rg 688][kt 64][h 2][quad 4][mrow 16]
//    entry = 8 fields (2 bits each) = k (kt*64 + h*32 + quad*8 .. +8) of
//    row rg*16+mrow, composed of the low bytes of two consecutive source
//    ints.  GEMM's per-(j,h) B-frag load is then 64 consecutive ushorts
//    (128 B) per wave = perfectly coalesced, L3-resident (11 MB).
// ---------------------------------------------------------------------------
__device__ __forceinline__ unsigned short f2bf_rne(float f) {
    unsigned u = __builtin_bit_cast(unsigned, f);
    u += 0x7fffu + ((u >> 16) & 1u);
    return (unsigned short)(u >> 16);
}

__global__ void prep_kernel(const float* __restrict__ x,
                            unsigned short* __restrict__ xb,
                            const int* __restrict__ pw,
                            unsigned short* __restrict__ pw2) {
    if (blockIdx.x < 8192) {
        size_t i = ((size_t)blockIdx.x * blockDim.x + threadIdx.x) * 8;
        float4 a = *(const float4*)(x + i);
        float4 b = *(const float4*)(x + i + 4);
        us8 o;
        o[0] = f2bf_rne(a.x); o[1] = f2bf_rne(a.y);
        o[2] = f2bf_rne(a.z); o[3] = f2bf_rne(a.w);
        o[4] = f2bf_rne(b.x); o[5] = f2bf_rne(b.y);
        o[6] = f2bf_rne(b.z); o[7] = f2bf_rne(b.w);
        *(us8*)(xb + i) = o;
    } else {
        // One block per rg (16 rows). Read 64 KB coalesced, transpose via
        // LDS (byte array, row stride 1028 to spread banks), write 16 KB
        // coalesced.
        __shared__ unsigned char lb[16 * 1028];
        const int rg = blockIdx.x - 8192;        // 0..687
        const int t  = threadIdx.x;              // 0..255
        const int4* src = (const int4*)(pw + (size_t)rg * 16384);
#pragma unroll
        for (int r = 0; r < 16; ++r) {
            int4 v = src[r * 256 + t];           // ints r*1024 + t*4 ..+3
            lb[r * 1028 + t * 4 + 0] = (unsigned char)(v.x & 0xFF);
            lb[r * 1028 + t * 4 + 1] = (unsigned char)(v.y & 0xFF);
            lb[r * 1028 + t * 4 + 2] = (unsigned char)(v.z & 0xFF);
            lb[r * 1028 + t * 4 + 3] = (unsigned char)(v.w & 0xFF);
        }
        __syncthreads();
        unsigned short* dst = pw2 + (size_t)rg * 8192;
#pragma unroll
        for (int i = 0; i < 32; ++i) {
            const int u    = i * 256 + t;        // 0..8191
            const int kt   = u >> 7;
            const int h    = (u >> 6) & 1;
            const int qd   = (u >> 4) & 3;
            const int mrow = u & 15;
            const int c0   = kt * 16 + h * 8 + qd * 2;
            dst[u] = (unsigned short)(lb[mrow * 1028 + c0] |
                                      (lb[mrow * 1028 + c0 + 1] << 8));
        }
    }
}

// ---------------------------------------------------------------------------
// Kernel 2: bf16 GEMM, 256x256 tile, BK=64, 8 waves, single-phase K-loop,
// B ENTIRELY IN REGISTERS (round-8 theory).
//
// R0-R7 evidence: five schedule structures all ~380-430 us; R7 cut HBM
// fetch 6x with ZERO speedup => not memory-bound.  The invariant cost is
// the LDS pipe (frag reads 2304 cyc/K-tile + staging writes) serialized
// against MFMA (2483 cyc).  Fix: a lane's B-frag = 8 consecutive k of one
// row = 2 PACKED BYTES.  Load the fragment-major packed ushort directly
// from global (128 B coalesced per (j,h) per wave, 11 MB L3-resident) and
// expand ushort -> bf16x8 in-register (perm-LUT, HW-validated in R7).
// Deletes all sB LDS reads/writes, the unpack 8-way write conflicts (R7's
// 1.1e7), and 64 KB of LDS.  New pipe budget per K-tile: LDS ~1792 cyc
// (A frags + A staging writes) < MFMA 2483 => matrix pipe is the floor.
// Unpack VALU (~70 instr/wave) rides the separate VALU pipe (m114).
//
// LDS: sA[2][2][256][32] = 64 KB only.
//  - slot for (row, seg) = seg ^ ((row>>1)&3); frag reads 2-way = free.
//  - A staging via global_load_lds unchanged (lane l: row chunk*16+l/4,
//    slot l&3, fetches global seg (l&3)^((l>>3)&3)).
//
// Per K-tile kt (buf=kt&1): stage A(kt+1)->sA[nbuf]; prefetch packed
// B(kt+1) ushorts (plain loads, drained by the barrier's vmcnt0 anyway,
// ~2500 cyc after issue); unpack pkb -> b frags per h; 16 ds_read_b128 A
// frags; 64 MFMA; rotate; one __syncthreads (vmcnt0+lgkm0 drain).
// Hazards: sA RAW/WAR cross-buffer around the single barrier (as R4);
// B path has no LDS hazards at all.
// ---------------------------------------------------------------------------
__device__ __forceinline__ void unpack_byte(unsigned b, unsigned& d_lo,
                                            unsigned& d_hi) {
    // b = 4 x 2-bit fields t0..t3 -> d_lo = bf16(t0-1),bf16(t1-1) packed,
    // d_hi = bf16(t2-1),bf16(t3-1).
    // bf16 LUT t=0..3 -> {-1,0,1,2}: 0xBF80,0x0000,0x3F80,0x4000
    const unsigned PA = 0x00800080u;   // lo-byte LUT
    const unsigned PB = 0x403F00BFu;   // hi-byte LUT (R6 bugfix, HW-passed R7)
    unsigned m0 = (b & 0xFu) * 0x00404101u;          // bytes [t0,t0,t1,t1]
    unsigned s0 = (m0 & 0x03030303u) | 0x00040004u;  // [t0|4, t0, t1|4, t1]
    d_lo = __builtin_amdgcn_perm(PA, PB, s0);
    unsigned m1 = (b >> 4) * 0x00404101u;            // bytes [t2,t2,t3,t3]
    unsigned s1 = (m1 & 0x03030303u) | 0x00040004u;
    d_hi = __builtin_amdgcn_perm(PA, PB, s1);
}

__device__ __forceinline__ bf16x8 unpack_us(unsigned short p) {
    unsigned d0, d1, d2, d3;
    unpack_byte(p & 0xFFu, d0, d1);       // k+0..3
    unpack_byte((unsigned)p >> 8, d2, d3); // k+4..7
    uint4 u = (uint4){d0, d1, d2, d3};
    return __builtin_bit_cast(bf16x8, u);
}

__global__ __launch_bounds__(512, 2) void gemm_kernel(
    const unsigned short* __restrict__ A,   // [M_DIM][IN_F] bf16 bits
    const unsigned short* __restrict__ P,   // packed W [rg][kt][h][quad][mrow]
    float* __restrict__ C,                  // [M_DIM][OUT_F]
    const float* __restrict__ scale_ptr) {
    constexpr int K  = IN_F;
    constexpr int N  = OUT_F;
    constexpr int NT = K / 64;              // 64 K-tiles

    __shared__ unsigned short sA[2][2][256][32];   // 64 KB

    const int tid  = threadIdx.x;
    const int wave = tid >> 6;
    const int lane = tid & 63;
    const int quad = lane >> 4;
    const int mrow = lane & 15;
    const int sw   = quad ^ ((mrow >> 1) & 3);          // A frag-read slot

    // A-staging lane decomposition
    const int srow = lane >> 2;                         // 0..15
    const int sseg = (lane & 3) ^ ((lane >> 3) & 3);    // source k-seg

    // Block swizzle: XCD x owns 86 consecutive tiles = 2 bm-rows x 43 bn.
    const int lin = blockIdx.x;             // 0..687
    const int xcd = lin & 7;
    const int q   = lin >> 3;               // 0..85
    const int bm  = xcd * 2 + q / 43;       // 0..15
    const int bn  = q % 43;                 // 0..42

    const int wm = (wave >> 2) * 128;       // wave M offset in tile
    const int wn = (wave & 3) * 64;         // wave N offset in tile

    const unsigned short* Ag = A + (size_t)bm * 256 * K;
    const int rgb = bn * 16 + (wn >> 4);    // wave's base row-group in P

    f32x4 acc[8][4];
#pragma unroll
    for (int i = 0; i < 8; i++)
#pragma unroll
        for (int j = 0; j < 4; j++) acc[i][j] = (f32x4){0.f, 0.f, 0.f, 0.f};

    // Stage A K-tile (both k-halves, 4 instr/wave) into sA[nb].
    auto STAGE_A = [&](int nb, int kbase) {
#pragma unroll
        for (int h = 0; h < 2; ++h) {
#pragma unroll
            for (int c = 0; c < 2; ++c) {
                const int chunk = wave * 2 + c;
                const int grow  = chunk * 16 + srow;
                const unsigned short* src =
                    Ag + (size_t)grow * K + kbase + h * 32 + sseg * 8;
                __builtin_amdgcn_global_load_lds(
                    (const __attribute__((address_space(1))) void*)src,
                    (__attribute__((address_space(3))) void*)
                        (&sA[nb][h][0][0] + chunk * 512),
                    16, 0, 0);
            }
        }
    };

    // Packed-B fragment address: 64 consecutive ushorts per (j,h) per wave.
    auto pidx = [&](int kt, int j, int h) -> size_t {
        return (((size_t)(rgb + j) * 64 + kt) * 2 + h) * 64 + lane;
    };

    // Prologue: stage A(0) -> buf0; load packed B(0).
    STAGE_A(0, 0);
    unsigned short pkb[8], npkb[8];
#pragma unroll
    for (int j = 0; j < 4; ++j)
#pragma unroll
        for (int h = 0; h < 2; ++h) pkb[j * 2 + h] = P[pidx(0, j, h)];
#pragma unroll
    for (int i = 0; i < 8; ++i) npkb[i] = 0;
    __syncthreads();

    for (int kt = 0; kt < NT; ++kt) {
        const int  buf  = kt & 1;
        const int  nbuf = buf ^ 1;
        const bool pf1  = (kt + 1 < NT);

        // Prefetch next tile: A -> LDS (DMA), packed B -> regs.
        if (pf1) {
            STAGE_A(nbuf, (kt + 1) * 64);
#pragma unroll
            for (int j = 0; j < 4; ++j)
#pragma unroll
                for (int h = 0; h < 2; ++h)
                    npkb[j * 2 + h] = P[pidx(kt + 1, j, h)];
        }

        // Compute: per k-half, unpack B in-register, read A frags, MFMA.
#pragma unroll
        for (int h = 0; h < 2; ++h) {
            bf16x8 a[8], b[4];
#pragma unroll
            for (int j = 0; j < 4; ++j) b[j] = unpack_us(pkb[j * 2 + h]);
#pragma unroll
            for (int t = 0; t < 8; ++t)
                a[t] = *(const bf16x8*)&sA[buf][h][wm + t * 16 + mrow][sw * 8];
#pragma unroll
            for (int t = 0; t < 8; ++t)
#pragma unroll
                for (int j = 0; j < 4; ++j)
                    acc[t][j] = __builtin_amdgcn_mfma_f32_16x16x32_bf16(
                        a[t], b[j], acc[t][j], 0, 0, 0);
        }

#pragma unroll
        for (int i = 0; i < 8; ++i) pkb[i] = npkb[i];

        __syncthreads();   // one barrier per K-tile (vmcnt+lgkm drain)
    }

    // Epilogue: C/D layout col=lane&15, row=quad*4+reg
    const float scale = *scale_ptr;
    float* Cg = C + (size_t)(bm * 256 + wm) * N + bn * 256 + wn;
#pragma unroll
    for (int i = 0; i < 8; ++i) {
#pragma unroll
        for (int j = 0; j < 4; ++j) {
#pragma unroll
            for (int r = 0; r < 4; ++r) {
                const int row = i * 16 + quad * 4 + r;
                const int col = j * 16 + mrow;
                Cg[(size_t)row * N + col] = acc[i][j][r] * scale;
            }
        }
    }
}

// ---------------------------------------------------------------------------
// Launch
// ---------------------------------------------------------------------------
extern "C" void kernel_launch(void* const* d_in, const int* in_sizes, int n_in,
                              void* d_out, int out_size, void* d_ws, size_t ws_size,
                              hipStream_t stream) {
    const float* x   = (const float*)d_in[0];     // [4,1024,4096] fp32
    const int* pw    = (const int*)d_in[1];       // [11008*4096/4] int32
    const float* wsc = (const float*)d_in[2];     // [1] fp32

    float* out = (float*)d_out;                   // [4,1024,11008] fp32

    unsigned short* xb  = (unsigned short*)d_ws;                       // 32 MB
    unsigned short* pw2 = (unsigned short*)((char*)d_ws
                          + (size_t)M_DIM * IN_F * 2);                 // 11 MB

    // fused prep: 8192 cvt blocks + 688 repack blocks
    prep_kernel<<<8192 + 688, 256, 0, stream>>>(x, xb, pw, pw2);

    // GEMM: 688 tiles = 16 (M/256) x 43 (N/256), 512 threads (8 waves)
    gemm_kernel<<<688, 512, 0, stream>>>(xb, pw2, out, wsc);
}